// Round 5
// baseline (1391.148 us; speedup 1.0000x reference)
//
#include <hip/hip_runtime.h>
#include <cstdint>
#include <cstddef>

#define T_STEPS 64
#define BATCH 512
#define IN_F 784
#define NKT 25          // k-tiles of 32 (784 padded to 800)
#define HID 2048
#define OUT_F 10

#define DEC_V 0.9f
#define DEC_I 0.8f
#define DT_V 0.1f
#define V_TH 0.5f

typedef __attribute__((ext_vector_type(8))) _Float16 f16x8;
typedef __attribute__((ext_vector_type(4))) float f32x4;

__device__ __forceinline__ void load_lds16h(const _Float16* g, _Float16* l) {
  __builtin_amdgcn_global_load_lds(
      (const __attribute__((address_space(1))) void*)g,
      (__attribute__((address_space(3))) void*)l, 16, 0, 0);
}

// ---------------------------------------------------------------------------
// Split fp32 [nrows,784] into f16 hi/lo in FRAGMENT-TILE order:
// tile (mt = row/16, kt = k/32) is 512 halves; within tile, lane l holds
// row (l&15), k-slice (l>>4)*8..+8 — exactly the MFMA A/B fragment, so the
// gemm can DMA tiles with global_load_lds (dest = base + lane*16B).
// ---------------------------------------------------------------------------
__global__ __launch_bounds__(256)
void split_frag(const float* __restrict__ src, _Float16* __restrict__ hiT,
                _Float16* __restrict__ loT) {
  __shared__ float xr[16][804];              // stride 804: 16B-aligned, 2-way banks
  const int mt = blockIdx.x;
  for (int i = threadIdx.x; i < 16 * IN_F; i += 256) {
    const int r = i / IN_F, c = i - r * IN_F;
    xr[r][c] = src[(size_t)(mt * 16 + r) * IN_F + c];
  }
  for (int i = threadIdx.x; i < 16 * 16; i += 256)
    xr[i >> 4][IN_F + (i & 15)] = 0.0f;      // pad k 784..799
  __syncthreads();

  const int l = threadIdx.x & 63;
  const int g = threadIdx.x >> 6;
  const int r = l & 15, q = l >> 4;
  for (int kt = g; kt < NKT; kt += 4) {
    const float* s = &xr[r][kt * 32 + q * 8];
    f16x8 h, lo;
#pragma unroll
    for (int j = 0; j < 8; ++j) {
      const float v = s[j];
      const _Float16 hh = (_Float16)v;       // RTN
      h[j] = hh;
      lo[j] = (_Float16)(v - (float)hh);
    }
    const size_t off = ((size_t)mt * NKT + kt) * 512 + l * 8;
    *(f16x8*)&hiT[off] = h;
    *(f16x8*)&loT[off] = lo;
  }
}

// ---------------------------------------------------------------------------
// MFMA GEMM: C[m,n] = sum_k A[m,k]*W[n,k] via 3x f16-split products.
//
// R9: occupancy play. Evidence: R4 (3 blocks/CU, simple drain loop) = 60%
// MfmaUtil beat every 1-block/CU schedule variant (R6/R7/R8, 43-54%) —
// independent barrier domains hide each other's drains (m114 mechanism).
// So: 128x128 tile, 4 waves (wave tile 64x64, acc 4x4, 48 MFMA + 16
// ds_read_b128 + 8 DMAs per wave-ktile), 32KB LDS -> 5 blocks/CU =
// 20 waves/CU. Simple R4-proven loop: sync; STAGE(kt); sync (vmcnt(0)
// drain — exposed per block, hidden by the 4 other resident blocks);
// reads+MFMA. XCD swizzle kept. No inline asm.
// ---------------------------------------------------------------------------
__global__ __launch_bounds__(256, 5)
void gemm_fc1(const _Float16* __restrict__ AhT, const _Float16* __restrict__ AlT,
              const _Float16* __restrict__ WhT, const _Float16* __restrict__ WlT,
              float* __restrict__ C) {
  __shared__ _Float16 __attribute__((aligned(16))) sAh[8 * 512];
  __shared__ _Float16 __attribute__((aligned(16))) sAl[8 * 512];
  __shared__ _Float16 __attribute__((aligned(16))) sWh[8 * 512];
  __shared__ _Float16 __attribute__((aligned(16))) sWl[8 * 512];

  const int tid = threadIdx.x;
  const int lane = tid & 63;
  const int wv = tid >> 6;                   // 0..3

  // Bijective XCD swizzle: nwg = 16 * (nrows/128), always % 8 == 0.
  const int nwg = gridDim.x * gridDim.y;
  const int bid = blockIdx.y * gridDim.x + blockIdx.x;   // hw dispatch order
  const int q = nwg >> 3;
  const int swz = (bid & 7) * q + (bid >> 3);
  const int bx = swz & 15;                               // gridDim.x == 16
  const int by = swz >> 4;

  const int bmT = by * 8;                    // A tile row base (m/16)
  const int bnT = bx * 8;                    // W tile row base (n/16)

  const int wr = wv >> 1;                    // 0..1: wave row (64 M each)
  const int wc = wv & 1;                     // 0..1: wave col (64 N each)
  const int col = lane & 15;
  const int quad = lane >> 4;

  f32x4 acc[4][4] = {};

  for (int kt = 0; kt < NKT; ++kt) {
    __syncthreads();                         // prev ktile's reads done
    // Each wave DMAs 2 A-tiles + 2 W-tiles (hi+lo each) = 8 DMAs / ktile.
#pragma unroll
    for (int j = 0; j < 2; ++j) {
      const int t = wv * 2 + j;
      const size_t ga = ((size_t)(bmT + t) * NKT + kt) * 512 + lane * 8;
      load_lds16h(AhT + ga, &sAh[t * 512]);
      load_lds16h(AlT + ga, &sAl[t * 512]);
      const size_t gw = ((size_t)(bnT + t) * NKT + kt) * 512 + lane * 8;
      load_lds16h(WhT + gw, &sWh[t * 512]);
      load_lds16h(WlT + gw, &sWl[t * 512]);
    }
    __syncthreads();                         // vmcnt(0) drain; hidden by TLP

    f16x8 fah[4], fal[4];
#pragma unroll
    for (int i = 0; i < 4; ++i) {
      fah[i] = *(const f16x8*)&sAh[(wr * 4 + i) * 512 + lane * 8];
      fal[i] = *(const f16x8*)&sAl[(wr * 4 + i) * 512 + lane * 8];
    }
#pragma unroll
    for (int nj = 0; nj < 4; ++nj) {
      const f16x8 fwh = *(const f16x8*)&sWh[(wc * 4 + nj) * 512 + lane * 8];
      const f16x8 fwl = *(const f16x8*)&sWl[(wc * 4 + nj) * 512 + lane * 8];
#pragma unroll
      for (int mi = 0; mi < 4; ++mi) {
        acc[mi][nj] = __builtin_amdgcn_mfma_f32_16x16x32_f16(fah[mi], fwh, acc[mi][nj], 0, 0, 0);
        acc[mi][nj] = __builtin_amdgcn_mfma_f32_16x16x32_f16(fah[mi], fwl, acc[mi][nj], 0, 0, 0);
        acc[mi][nj] = __builtin_amdgcn_mfma_f32_16x16x32_f16(fal[mi], fwh, acc[mi][nj], 0, 0, 0);
      }
    }
  }

  // C/D layout: col = lane&15, row = quad*4 + reg (R3/R4-verified).
  // nj innermost: consecutive stores walk consecutive 64B of one line.
  const int rowb = by * 128 + wr * 64;
  const int colb = bx * 128 + wc * 64;
#pragma unroll
  for (int mi = 0; mi < 4; ++mi)
#pragma unroll
    for (int r = 0; r < 4; ++r) {
      const size_t rowo = (size_t)(rowb + mi * 16 + quad * 4 + r) * HID;
#pragma unroll
      for (int nj = 0; nj < 4; ++nj)
        C[rowo + colb + nj * 16 + col] = acc[mi][nj][r];
    }
}

// ---------------------------------------------------------------------------
// Fused LIF scan + output projection partials (R4-verified, unchanged).
// ---------------------------------------------------------------------------
__global__ __launch_bounds__(256)
void lif_out(const float* __restrict__ cur, const float* __restrict__ wo,
             float* __restrict__ v1, float* __restrict__ i1,
             float* __restrict__ outP, int tc, int t0) {
  __shared__ _Float16 zL[T_STEPS][264];
  __shared__ _Float16 wT[16][264];

  const int tid = threadIdx.x;
  const int hc = blockIdx.x;
  const int b = blockIdx.y;
  const int hb = hc * 256;

  for (int i = tid; i < 16 * 256; i += 256) {
    const int n = i >> 8, k = i & 255;
    wT[n][k] = (n < OUT_F) ? (_Float16)wo[(size_t)n * HID + hb + k] : (_Float16)0.f;
  }

  const int sidx = b * HID + hb + tid;
  float v = v1[sidx];
  float ci = i1[sidx];
#pragma unroll 4
  for (int t = 0; t < tc; ++t) {
    const float c = cur[(size_t)t * (BATCH * HID) + sidx];
    const float vd = DEC_V * v + DT_V * ci;
    const float z = (vd > V_TH) ? 1.0f : 0.0f;
    v = (1.0f - z) * vd;
    ci = DEC_I * ci + c;
    zL[t][tid] = (_Float16)z;
  }
  v1[sidx] = v;
  i1[sidx] = ci;
  __syncthreads();

  const int wv = tid >> 6;
  const int lane = tid & 63;
  const int col = lane & 15;
  const int quad = lane >> 4;
  f32x4 acc = {};
  const _Float16* za = &zL[wv * 16 + col][0];
  const _Float16* wb = &wT[col][0];
#pragma unroll
  for (int ks = 0; ks < 8; ++ks) {
    f16x8 a = *(const f16x8*)(za + ks * 32 + quad * 8);
    f16x8 bb = *(const f16x8*)(wb + ks * 32 + quad * 8);
    acc = __builtin_amdgcn_mfma_f32_16x16x32_f16(a, bb, acc, 0, 0, 0);
  }
  if (col < OUT_F) {
#pragma unroll
    for (int r = 0; r < 4; ++r) {
      const int t = wv * 16 + quad * 4 + r;
      if (t < tc)
        outP[(((size_t)hc * T_STEPS + (t0 + t)) * BATCH + b) * OUT_F + col] = acc[r];
    }
  }
}

// ---------------------------------------------------------------------------
// LI readout: sum 8 chunk partials, scan, max. One thread per (b,o).
// ---------------------------------------------------------------------------
__global__ __launch_bounds__(256)
void li_scan(const float* __restrict__ outP, float* __restrict__ out) {
  const int idx = blockIdx.x * 256 + threadIdx.x;
  if (idx >= BATCH * OUT_F) return;
  float vo = 0.f, io = 0.f, vmax = 0.f;
  for (int t = 0; t < T_STEPS; ++t) {
    float oc = 0.f;
#pragma unroll
    for (int hc = 0; hc < 8; ++hc)
      oc += outP[((size_t)hc * T_STEPS + t) * (BATCH * OUT_F) + idx];
    const float von = DEC_V * vo + DT_V * io;
    io = DEC_I * io + oc;
    vo = von;
    vmax = fmaxf(vmax, von);
  }
  out[idx] = vmax;
}

__global__ void zero_state(float* __restrict__ p, int n) {
  int i = blockIdx.x * 256 + threadIdx.x;
  if (i < n) p[i] = 0.0f;
}

// ---------------------------------------------------------------------------
extern "C" void kernel_launch(void* const* d_in, const int* in_sizes, int n_in,
                              void* d_out, int out_size, void* d_ws, size_t ws_size,
                              hipStream_t stream) {
  const float* x  = (const float*)d_in[0];  // [T*B, 784]
  const float* w1 = (const float*)d_in[1];  // [2048, 784]
  const float* wo = (const float*)d_in[2];  // [10, 2048]
  float* out = (float*)d_out;               // [512, 10]

  const size_t BH = (size_t)BATCH * HID;
  const size_t WT_HALVES = (size_t)(HID / 16) * NKT * 512;   // per W array

  // fixed: v1 | i1 | outP[8][T*B*10] | WhT | WlT ; chunk: cur | AhT | AlT
  float* v1 = (float*)d_ws;
  float* i1 = v1 + BH;
  float* outP = i1 + BH;
  _Float16* WhT = (_Float16*)(outP + (size_t)8 * T_STEPS * BATCH * OUT_F);
  _Float16* WlT = WhT + WT_HALVES;
  char* chunk0 = (char*)(WlT + WT_HALVES);

  const size_t base_bytes = (size_t)(chunk0 - (char*)d_ws);
  // per step: cur f32 [512,2048] + AhT/AlT f16 [32 tiles][25][512]
  const size_t per_step = BH * 4 + (size_t)2 * 32 * NKT * 512 * 2;
  int Tc = T_STEPS;
  while (Tc > 1 && base_bytes + (size_t)Tc * per_step > ws_size) Tc >>= 1;

  float* cur = (float*)chunk0;
  _Float16* AhT = (_Float16*)(cur + (size_t)Tc * BH);
  _Float16* AlT = AhT + (size_t)Tc * 32 * NKT * 512;

  split_frag<<<HID / 16, 256, 0, stream>>>(w1, WhT, WlT);
  zero_state<<<(int)((2 * BH + 255) / 256), 256, 0, stream>>>(v1, (int)(2 * BH));

  for (int t0 = 0; t0 < T_STEPS; t0 += Tc) {
    const int tc = (T_STEPS - t0 < Tc) ? (T_STEPS - t0) : Tc;
    const int nrows = tc * BATCH;
    split_frag<<<nrows / 16, 256, 0, stream>>>(x + (size_t)t0 * BATCH * IN_F, AhT, AlT);
    dim3 grid(HID / 128, nrows / 128);       // 128x128 block tile, 256 thr
    gemm_fc1<<<grid, 256, 0, stream>>>(AhT, AlT, WhT, WlT, cur);
    dim3 lgrid(HID / 256, BATCH);
    lif_out<<<lgrid, 256, 0, stream>>>(cur, wo, v1, i1, outP, tc, t0);
  }
  li_scan<<<(BATCH * OUT_F + 255) / 256, 256, 0, stream>>>(outP, out);
}

// Round 6
// 601.786 us; speedup vs baseline: 2.3117x; 2.3117x over previous
//
#include <hip/hip_runtime.h>
#include <cstdint>
#include <cstddef>

#define T_STEPS 64
#define BATCH 512
#define IN_F 784
#define NKT 25          // k-tiles of 32 (784 padded to 800)
#define HID 2048
#define OUT_F 10

#define DEC_V 0.9f
#define DEC_I 0.8f
#define DT_V 0.1f
#define V_TH 0.5f

typedef __attribute__((ext_vector_type(8))) _Float16 f16x8;
typedef __attribute__((ext_vector_type(4))) float f32x4;

__device__ __forceinline__ void load_lds16h(const _Float16* g, _Float16* l) {
  __builtin_amdgcn_global_load_lds(
      (const __attribute__((address_space(1))) void*)g,
      (__attribute__((address_space(3))) void*)l, 16, 0, 0);
}

// ---------------------------------------------------------------------------
// Split fp32 [nrows,784] into f16 hi/lo in FRAGMENT-TILE order:
// tile (mt = row/16, kt = k/32) is 512 halves; within tile, lane l holds
// row (l&15), k-slice (l>>4)*8..+8 — exactly the MFMA A/B fragment, so the
// gemm can DMA tiles with global_load_lds (dest = base + lane*16B).
// ---------------------------------------------------------------------------
__global__ __launch_bounds__(256)
void split_frag(const float* __restrict__ src, _Float16* __restrict__ hiT,
                _Float16* __restrict__ loT) {
  __shared__ float xr[16][804];              // stride 804: 16B-aligned, 2-way banks
  const int mt = blockIdx.x;
  for (int i = threadIdx.x; i < 16 * IN_F; i += 256) {
    const int r = i / IN_F, c = i - r * IN_F;
    xr[r][c] = src[(size_t)(mt * 16 + r) * IN_F + c];
  }
  for (int i = threadIdx.x; i < 16 * 16; i += 256)
    xr[i >> 4][IN_F + (i & 15)] = 0.0f;      // pad k 784..799
  __syncthreads();

  const int l = threadIdx.x & 63;
  const int g = threadIdx.x >> 6;
  const int r = l & 15, q = l >> 4;
  for (int kt = g; kt < NKT; kt += 4) {
    const float* s = &xr[r][kt * 32 + q * 8];
    f16x8 h, lo;
#pragma unroll
    for (int j = 0; j < 8; ++j) {
      const float v = s[j];
      const _Float16 hh = (_Float16)v;       // RTN
      h[j] = hh;
      lo[j] = (_Float16)(v - (float)hh);
    }
    const size_t off = ((size_t)mt * NKT + kt) * 512 + l * 8;
    *(f16x8*)&hiT[off] = h;
    *(f16x8*)&loT[off] = lo;
  }
}

// ---------------------------------------------------------------------------
// MFMA GEMM: C[m,n] = sum_k A[m,k]*W[n,k] via 3x f16-split products.
//
// R10 = R4 restored EXACTLY (best measured: 256-259us, 60% MfmaUtil,
// VGPR 108, ~2 blocks/CU — block-level TLP hides the per-ktile drain
// better than every hand schedule tried in R5-R9), plus two verified-
// mechanism adds:
//  - bijective XCD swizzle (R5-R8: FETCH 423->154MB; here it turns the
//    per-ktile vmcnt(0) drain from an HBM-miss wait (~900cy) into an
//    L2/L3-hit wait (~200-300cy)),
//  - nj-innermost C-store (consecutive 64B segments of the same rows;
//    probes the 262-vs-134MB WRITE amplification).
// Block tile 128(M) x 256(N), 4 waves, each wave 64x128 = 4x8 tiles of
// 16x16x32: 96 MFMA : 24 ds_read_b128 : 12 DMAs per wave-ktile.
// ---------------------------------------------------------------------------
__global__ __launch_bounds__(256, 2)
void gemm_fc1(const _Float16* __restrict__ AhT, const _Float16* __restrict__ AlT,
              const _Float16* __restrict__ WhT, const _Float16* __restrict__ WlT,
              float* __restrict__ C) {
  __shared__ _Float16 __attribute__((aligned(16))) sAh[8 * 512];
  __shared__ _Float16 __attribute__((aligned(16))) sAl[8 * 512];
  __shared__ _Float16 __attribute__((aligned(16))) sWh[16 * 512];
  __shared__ _Float16 __attribute__((aligned(16))) sWl[16 * 512];

  const int tid = threadIdx.x;
  const int lane = tid & 63;
  const int wv = tid >> 6;

  // Bijective XCD swizzle: nwg = 8 * (nrows/128), always % 8 == 0.
  // XCD k gets a contiguous 1/8 M-band across all 8 N-strips.
  const int nwg = gridDim.x * gridDim.y;
  const int bid = blockIdx.y * gridDim.x + blockIdx.x;   // hw dispatch order
  const int q = nwg >> 3;
  const int swz = (bid & 7) * q + (bid >> 3);
  const int bx = swz & 7;                                // gridDim.x == 8
  const int by = swz >> 3;

  const int bmT = by * 8;                    // A tile row base (m/16)
  const int bnT = bx * 16;                   // W tile row base (n/16)

  const int wrT = (wv >> 1) * 4;             // wave's A-tile offset (0/4)
  const int wcT = (wv & 1) * 8;              // wave's W-tile offset (0/8)
  const int col = lane & 15;
  const int quad = lane >> 4;

  f32x4 acc[4][8] = {};

  for (int kt = 0; kt < NKT; ++kt) {
    __syncthreads();
#pragma unroll
    for (int j = 0; j < 2; ++j) {            // A tiles wv*2, wv*2+1
      const int t = wv * 2 + j;
      const size_t go = ((size_t)(bmT + t) * NKT + kt) * 512 + lane * 8;
      load_lds16h(AhT + go, sAh + t * 512);
      load_lds16h(AlT + go, sAl + t * 512);
    }
#pragma unroll
    for (int j = 0; j < 4; ++j) {            // W tiles wv*4 .. wv*4+3
      const int t = wv * 4 + j;
      const size_t go = ((size_t)(bnT + t) * NKT + kt) * 512 + lane * 8;
      load_lds16h(WhT + go, sWh + t * 512);
      load_lds16h(WlT + go, sWl + t * 512);
    }
    __syncthreads();

    f16x8 fah[4], fal[4];
#pragma unroll
    for (int i = 0; i < 4; ++i) {
      fah[i] = *(const f16x8*)&sAh[(wrT + i) * 512 + lane * 8];
      fal[i] = *(const f16x8*)&sAl[(wrT + i) * 512 + lane * 8];
    }
#pragma unroll
    for (int ni = 0; ni < 8; ++ni) {
      const f16x8 fwh = *(const f16x8*)&sWh[(wcT + ni) * 512 + lane * 8];
      const f16x8 fwl = *(const f16x8*)&sWl[(wcT + ni) * 512 + lane * 8];
#pragma unroll
      for (int mi = 0; mi < 4; ++mi) {
        acc[mi][ni] = __builtin_amdgcn_mfma_f32_16x16x32_f16(fah[mi], fwh, acc[mi][ni], 0, 0, 0);
        acc[mi][ni] = __builtin_amdgcn_mfma_f32_16x16x32_f16(fah[mi], fwl, acc[mi][ni], 0, 0, 0);
        acc[mi][ni] = __builtin_amdgcn_mfma_f32_16x16x32_f16(fal[mi], fwh, acc[mi][ni], 0, 0, 0);
      }
    }
  }

  // C/D layout: col = lane&15, row = quad*4 + reg (R3/R4-verified).
  // ni innermost: per (mi,r) the 8 stores fill consecutive 64B segments
  // of 4 rows (quad-split), maximizing full-line writeback.
  const int rowb = by * 128 + (wv >> 1) * 64;
  const int colb = bx * 256 + (wv & 1) * 128;
#pragma unroll
  for (int mi = 0; mi < 4; ++mi)
#pragma unroll
    for (int r = 0; r < 4; ++r) {
      const size_t rowo = (size_t)(rowb + mi * 16 + quad * 4 + r) * HID;
#pragma unroll
      for (int ni = 0; ni < 8; ++ni)
        C[rowo + colb + ni * 16 + col] = acc[mi][ni][r];
    }
}

// ---------------------------------------------------------------------------
// Fused LIF scan + output projection partials (R4-verified, unchanged).
// ---------------------------------------------------------------------------
__global__ __launch_bounds__(256)
void lif_out(const float* __restrict__ cur, const float* __restrict__ wo,
             float* __restrict__ v1, float* __restrict__ i1,
             float* __restrict__ outP, int tc, int t0) {
  __shared__ _Float16 zL[T_STEPS][264];
  __shared__ _Float16 wT[16][264];

  const int tid = threadIdx.x;
  const int hc = blockIdx.x;
  const int b = blockIdx.y;
  const int hb = hc * 256;

  for (int i = tid; i < 16 * 256; i += 256) {
    const int n = i >> 8, k = i & 255;
    wT[n][k] = (n < OUT_F) ? (_Float16)wo[(size_t)n * HID + hb + k] : (_Float16)0.f;
  }

  const int sidx = b * HID + hb + tid;
  float v = v1[sidx];
  float ci = i1[sidx];
#pragma unroll 4
  for (int t = 0; t < tc; ++t) {
    const float c = cur[(size_t)t * (BATCH * HID) + sidx];
    const float vd = DEC_V * v + DT_V * ci;
    const float z = (vd > V_TH) ? 1.0f : 0.0f;
    v = (1.0f - z) * vd;
    ci = DEC_I * ci + c;
    zL[t][tid] = (_Float16)z;
  }
  v1[sidx] = v;
  i1[sidx] = ci;
  __syncthreads();

  const int wv = tid >> 6;
  const int lane = tid & 63;
  const int col = lane & 15;
  const int quad = lane >> 4;
  f32x4 acc = {};
  const _Float16* za = &zL[wv * 16 + col][0];
  const _Float16* wb = &wT[col][0];
#pragma unroll
  for (int ks = 0; ks < 8; ++ks) {
    f16x8 a = *(const f16x8*)(za + ks * 32 + quad * 8);
    f16x8 bb = *(const f16x8*)(wb + ks * 32 + quad * 8);
    acc = __builtin_amdgcn_mfma_f32_16x16x32_f16(a, bb, acc, 0, 0, 0);
  }
  if (col < OUT_F) {
#pragma unroll
    for (int r = 0; r < 4; ++r) {
      const int t = wv * 16 + quad * 4 + r;
      if (t < tc)
        outP[(((size_t)hc * T_STEPS + (t0 + t)) * BATCH + b) * OUT_F + col] = acc[r];
    }
  }
}

// ---------------------------------------------------------------------------
// LI readout: sum 8 chunk partials, scan, max. One thread per (b,o).
// ---------------------------------------------------------------------------
__global__ __launch_bounds__(256)
void li_scan(const float* __restrict__ outP, float* __restrict__ out) {
  const int idx = blockIdx.x * 256 + threadIdx.x;
  if (idx >= BATCH * OUT_F) return;
  float vo = 0.f, io = 0.f, vmax = 0.f;
  for (int t = 0; t < T_STEPS; ++t) {
    float oc = 0.f;
#pragma unroll
    for (int hc = 0; hc < 8; ++hc)
      oc += outP[((size_t)hc * T_STEPS + t) * (BATCH * OUT_F) + idx];
    const float von = DEC_V * vo + DT_V * io;
    io = DEC_I * io + oc;
    vo = von;
    vmax = fmaxf(vmax, von);
  }
  out[idx] = vmax;
}

__global__ void zero_state(float* __restrict__ p, int n) {
  int i = blockIdx.x * 256 + threadIdx.x;
  if (i < n) p[i] = 0.0f;
}

// ---------------------------------------------------------------------------
extern "C" void kernel_launch(void* const* d_in, const int* in_sizes, int n_in,
                              void* d_out, int out_size, void* d_ws, size_t ws_size,
                              hipStream_t stream) {
  const float* x  = (const float*)d_in[0];  // [T*B, 784]
  const float* w1 = (const float*)d_in[1];  // [2048, 784]
  const float* wo = (const float*)d_in[2];  // [10, 2048]
  float* out = (float*)d_out;               // [512, 10]

  const size_t BH = (size_t)BATCH * HID;
  const size_t WT_HALVES = (size_t)(HID / 16) * NKT * 512;   // per W array

  // fixed: v1 | i1 | outP[8][T*B*10] | WhT | WlT ; chunk: cur | AhT | AlT
  float* v1 = (float*)d_ws;
  float* i1 = v1 + BH;
  float* outP = i1 + BH;
  _Float16* WhT = (_Float16*)(outP + (size_t)8 * T_STEPS * BATCH * OUT_F);
  _Float16* WlT = WhT + WT_HALVES;
  char* chunk0 = (char*)(WlT + WT_HALVES);

  const size_t base_bytes = (size_t)(chunk0 - (char*)d_ws);
  // per step: cur f32 [512,2048] + AhT/AlT f16 [32 tiles][25][512]
  const size_t per_step = BH * 4 + (size_t)2 * 32 * NKT * 512 * 2;
  int Tc = T_STEPS;
  while (Tc > 1 && base_bytes + (size_t)Tc * per_step > ws_size) Tc >>= 1;

  float* cur = (float*)chunk0;
  _Float16* AhT = (_Float16*)(cur + (size_t)Tc * BH);
  _Float16* AlT = AhT + (size_t)Tc * 32 * NKT * 512;

  split_frag<<<HID / 16, 256, 0, stream>>>(w1, WhT, WlT);
  zero_state<<<(int)((2 * BH + 255) / 256), 256, 0, stream>>>(v1, (int)(2 * BH));

  for (int t0 = 0; t0 < T_STEPS; t0 += Tc) {
    const int tc = (T_STEPS - t0 < Tc) ? (T_STEPS - t0) : Tc;
    const int nrows = tc * BATCH;
    split_frag<<<nrows / 16, 256, 0, stream>>>(x + (size_t)t0 * BATCH * IN_F, AhT, AlT);
    dim3 grid(HID / 256, nrows / 128);
    gemm_fc1<<<grid, 256, 0, stream>>>(AhT, AlT, WhT, WlT, cur);
    dim3 lgrid(HID / 256, BATCH);
    lif_out<<<lgrid, 256, 0, stream>>>(cur, wo, v1, i1, outP, tc, t0);
  }
  li_scan<<<(BATCH * OUT_F + 255) / 256, 256, 0, stream>>>(outP, out);
}